// Round 7
// baseline (236.819 us; speedup 1.0000x reference)
//
#include <hip/hip_runtime.h>
#include <math.h>

#define N 8192
#define D 128
#define NC 256
#define NT 64                    // 128-wide tiles per dim
#define NBLK (NT * (NT + 1) / 2) // 2080
#define KC 32                    // k-chunk depth
#define LDSW 132                 // 128 + 4 pad

typedef float v2f __attribute__((ext_vector_type(2)));

__device__ __forceinline__ v2f fma2(v2f a, v2f b, v2f c) {
#if __has_builtin(__builtin_elementwise_fma)
    return __builtin_elementwise_fma(a, b, c);
#else
    v2f r; r.x = fmaf(a.x, b.x, c.x); r.y = fmaf(a.y, b.y, c.y); return r;
#endif
}

// ---------------------------------------------------------------------------
// Kernel 1: normalize 64 rows/block via LDS transpose; coalesced xnT writes;
// accumulates label histogram (hist pre-zeroed); also inits pos/neg packs
// (visible to miner via inter-dispatch ordering on the same stream).
// ---------------------------------------------------------------------------
__global__ __launch_bounds__(256) void normalize_kernel(
    const float* __restrict__ x, const int* __restrict__ labels,
    float* __restrict__ xnT, float* __restrict__ sq, int* __restrict__ hist,
    unsigned long long* __restrict__ pos_pack,
    unsigned long long* __restrict__ neg_pack) {
    __shared__ float Xs[64 * 129];
    __shared__ float norms[64];
    const int t = threadIdx.x;
    const int r0 = blockIdx.x * 64;

    // init best-packs: 32768 threads cover 8192 entries
    {
        const int g = blockIdx.x * 256 + t;
        if (g < N) { pos_pack[g] = 0ULL; neg_pack[g] = ~0ULL; }
    }

    // phase 1: load 64x128 block (coalesced float4)
#pragma unroll
    for (int p = 0; p < 8; ++p) {
        const int lin = p * 256 + t;
        const int row = lin >> 5;
        const int c0 = (lin & 31) << 2;
        const float4 v = *(const float4*)(x + (size_t)(r0 + row) * D + c0);
        float* dst = &Xs[row * 129 + c0];
        dst[0] = v.x; dst[1] = v.y; dst[2] = v.z; dst[3] = v.w;
    }
    __syncthreads();

    // phase 2: 4 threads per row -> norm, then sum of normalized squares
    {
        const int r = t >> 2, q = t & 3;
        const float* src = &Xs[r * 129 + q * 32];
        float s = 0.f;
#pragma unroll
        for (int i = 0; i < 32; ++i) s = fmaf(src[i], src[i], s);
        s += __shfl_xor(s, 1, 64);
        s += __shfl_xor(s, 2, 64);
        const float nrm = sqrtf(s);
        float t2 = 0.f;
#pragma unroll
        for (int i = 0; i < 32; ++i) {
            const float n = src[i] / nrm;
            t2 = fmaf(n, n, t2);
        }
        t2 += __shfl_xor(t2, 1, 64);
        t2 += __shfl_xor(t2, 2, 64);
        if (q == 0) { sq[r0 + r] = t2; norms[r] = nrm; }
    }
    __syncthreads();

    // phase 3: transposed write; lane=row -> 256 B contiguous per k
    {
        const int r_off = t & 63;
        const int w = t >> 6;
        const float nrm = norms[r_off];
#pragma unroll
        for (int m = 0; m < 32; ++m) {
            const int k = w * 32 + m;
            xnT[(size_t)k * N + r0 + r_off] = Xs[r_off * 129 + k] / nrm;
        }
    }

    // histogram of this block's 64 labels
    if (t < 64) atomicAdd(&hist[labels[r0 + t]], 1);
}

// ---------------------------------------------------------------------------
// Kernel 2: symmetric 128x128-tile Gram + fused arg-reductions, 8x8/thread.
// R7: software-pipelined k-loop (register prefetch of k+1 fragments) +
// float2-packed FMA (v_pk_fma_f32 candidate). Plain launch_bounds(256):
// occupancy hints pin VGPR to 64 and spill (R4/R5 evidence).
// ---------------------------------------------------------------------------
__device__ __forceinline__ unsigned int fbits(float f) {
    union { float f; unsigned int u; } x; x.f = f; return x.u;
}
__device__ __forceinline__ unsigned long long pack_pos(float v, int j) {
    return ((unsigned long long)fbits(v) << 32) | (unsigned int)(8191 - j);
}
__device__ __forceinline__ unsigned long long pack_neg(float v, int j) {
    return ((unsigned long long)fbits(v) << 32) | (unsigned int)j;
}
__device__ __forceinline__ void red_max(float& v, int& j, int mask) {
    const float ov = __shfl_xor(v, mask, 64);
    const int   oj = __shfl_xor(j, mask, 64);
    if (ov > v || (ov == v && oj < j)) { v = ov; j = oj; }
}
__device__ __forceinline__ void red_min(float& v, int& j, int mask) {
    const float ov = __shfl_xor(v, mask, 64);
    const int   oj = __shfl_xor(j, mask, 64);
    if (ov < v || (ov == v && oj < j)) { v = ov; j = oj; }
}

__global__ __launch_bounds__(256) void miner_kernel(
    const float* __restrict__ xnT, const float* __restrict__ sq,
    const int* __restrict__ labels,
    unsigned long long* __restrict__ pos_pack,
    unsigned long long* __restrict__ neg_pack) {
    __shared__ float As[KC * LDSW];   // 16.5 KB; reused as u64 scratch later
    __shared__ float Bs[KC * LDSW];   // 16.5 KB
    __shared__ float sqI[128], sqJ[128];
    __shared__ int   lbI[128], lbJ[128];

    const int t  = threadIdx.x;
    const int tx = t & 15;
    const int ty = t >> 4;

    // decode upper-triangular (bi, bj), bi <= bj, NT=64
    const int b = blockIdx.x;
    int bi = (int)((129.0f - sqrtf(16641.0f - 8.0f * (float)b)) * 0.5f);
    while (bi > 0 && (bi * NT - bi * (bi - 1) / 2) > b) --bi;
    while (((bi + 1) * NT - (bi + 1) * bi / 2) <= b) ++bi;
    const int bj = bi + (b - (bi * NT - bi * (bi - 1) / 2));
    const int I0 = bi * 128, J0 = bj * 128;
    const bool diag = (bi == bj);

    if (t < 128) { sqI[t] = sq[I0 + t]; lbI[t] = labels[I0 + t]; }
    else         { sqJ[t - 128] = sq[J0 + t - 128]; lbJ[t - 128] = labels[J0 + t - 128]; }

    const int cA = 4 * ty;   // rows 4ty..+3 and 64+4ty..+3
    const int cB = 4 * tx;   // cols 4tx..+3 and 64+4tx..+3
    const float* gA = xnT + I0;
    const float* gB = xnT + J0;

    v2f acc2[8][4];
#pragma unroll
    for (int ri = 0; ri < 8; ++ri)
#pragma unroll
        for (int cp = 0; cp < 4; ++cp) { acc2[ri][cp].x = 0.f; acc2[ri][cp].y = 0.f; }

    for (int kc = 0; kc < D; kc += KC) {
        __syncthreads();
#pragma unroll
        for (int p = 0; p < 4; ++p) {
            const int lin = p * 256 + t;
            const int k = lin >> 5;
            const int c0 = (lin & 31) << 2;
            *(float4*)&As[k * LDSW + c0] =
                *(const float4*)(gA + (size_t)(kc + k) * N + c0);
            *(float4*)&Bs[k * LDSW + c0] =
                *(const float4*)(gB + (size_t)(kc + k) * N + c0);
        }
        __syncthreads();

        // software pipeline: head loads, then prefetch k+1 while FMAing k
        float4 a0 = *(const float4*)&As[cA];
        float4 a1 = *(const float4*)&As[64 + cA];
        float4 b0 = *(const float4*)&Bs[cB];
        float4 b1 = *(const float4*)&Bs[64 + cB];
#pragma unroll 4
        for (int k = 0; k < KC; ++k) {
            const int kn = (k + 1) & (KC - 1);   // last prefetch discarded
            const float4 na0 = *(const float4*)&As[kn * LDSW + cA];
            const float4 na1 = *(const float4*)&As[kn * LDSW + 64 + cA];
            const float4 nb0 = *(const float4*)&Bs[kn * LDSW + cB];
            const float4 nb1 = *(const float4*)&Bs[kn * LDSW + 64 + cB];

            const float ar[8] = {a0.x, a0.y, a0.z, a0.w, a1.x, a1.y, a1.z, a1.w};
            v2f bp[4];
            bp[0].x = b0.x; bp[0].y = b0.y;
            bp[1].x = b0.z; bp[1].y = b0.w;
            bp[2].x = b1.x; bp[2].y = b1.y;
            bp[3].x = b1.z; bp[3].y = b1.w;
#pragma unroll
            for (int ri = 0; ri < 8; ++ri) {
                v2f av; av.x = ar[ri]; av.y = ar[ri];
#pragma unroll
                for (int cp = 0; cp < 4; ++cp)
                    acc2[ri][cp] = fma2(av, bp[cp], acc2[ri][cp]);
            }
            a0 = na0; a1 = na1; b0 = nb0; b1 = nb1;
        }
    }

    // unpack to scalar 8x8
    float acc[8][8];
#pragma unroll
    for (int ri = 0; ri < 8; ++ri)
#pragma unroll
        for (int cp = 0; cp < 4; ++cp) {
            acc[ri][2 * cp]     = acc2[ri][cp].x;
            acc[ri][2 * cp + 1] = acc2[ri][cp].y;
        }

    // local row/col offsets of this thread's fragment
    int lrow[8], lcol[8];
#pragma unroll
    for (int i = 0; i < 8; ++i) {
        lrow[i] = 4 * ty + (i & 3) + 64 * (i >> 2);
        lcol[i] = 4 * tx + (i & 3) + 64 * (i >> 2);
    }
    int li[8], lj[8];
#pragma unroll
    for (int i = 0; i < 8; ++i) { li[i] = lbI[lrow[i]]; lj[i] = lbJ[lcol[i]]; }

    // d2 in place
#pragma unroll
    for (int ri = 0; ri < 8; ++ri) {
        const float si = sqI[lrow[ri]];
#pragma unroll
        for (int ci = 0; ci < 8; ++ci)
            acc[ri][ci] = fmaxf(si + sqJ[lcol[ci]] - 2.0f * acc[ri][ci], 0.0f);
    }

    // I-side: per-row best over this thread's 8 cols (ascending j), reduce
    // across tx (masks 1..8, index tie-break), commit.
    {
        float bpv[8], bnv[8]; int bpj[8], bnj[8];
#pragma unroll
        for (int ri = 0; ri < 8; ++ri) {
            bpv[ri] = -1.0f; bpj[ri] = 0; bnv[ri] = INFINITY; bnj[ri] = 0;
            const int row = I0 + lrow[ri];
#pragma unroll
            for (int ci = 0; ci < 8; ++ci) {
                const int col = J0 + lcol[ci];
                const bool same = (li[ri] == lj[ci]);
                const float vp = (same && row != col) ? acc[ri][ci] : 0.0f;
                if (vp > bpv[ri]) { bpv[ri] = vp; bpj[ri] = col; }
                const float vn = same ? INFINITY : acc[ri][ci];
                if (vn < bnv[ri]) { bnv[ri] = vn; bnj[ri] = col; }
            }
        }
#pragma unroll
        for (int m = 1; m < 16; m <<= 1)
#pragma unroll
            for (int ri = 0; ri < 8; ++ri) {
                red_max(bpv[ri], bpj[ri], m);
                red_min(bnv[ri], bnj[ri], m);
            }
        if (tx == 0) {
#pragma unroll
            for (int ri = 0; ri < 8; ++ri) {
                atomicMax(&pos_pack[I0 + lrow[ri]], pack_pos(bpv[ri], bpj[ri]));
                atomicMin(&neg_pack[I0 + lrow[ri]], pack_neg(bnv[ri], bnj[ri]));
            }
        }
    }

    // J-side (skip on diagonal): per-col best over 8 rows (ascending), reduce
    // across in-wave ty (masks 16,32), cross-wave merge via LDS, one commit/col.
    if (!diag) {
        float bpv[8], bnv[8]; int bpj[8], bnj[8];
#pragma unroll
        for (int ci = 0; ci < 8; ++ci) {
            bpv[ci] = -1.0f; bpj[ci] = 0; bnv[ci] = INFINITY; bnj[ci] = 0;
#pragma unroll
            for (int ri = 0; ri < 8; ++ri) {
                const int row = I0 + lrow[ri];
                const bool same = (li[ri] == lj[ci]);   // no self off-diagonal
                const float vp = same ? acc[ri][ci] : 0.0f;
                if (vp > bpv[ci]) { bpv[ci] = vp; bpj[ci] = row; }
                const float vn = same ? INFINITY : acc[ri][ci];
                if (vn < bnv[ci]) { bnv[ci] = vn; bnj[ci] = row; }
            }
        }
#pragma unroll
        for (int m = 16; m < 64; m <<= 1)
#pragma unroll
            for (int ci = 0; ci < 8; ++ci) {
                red_max(bpv[ci], bpj[ci], m);
                red_min(bnv[ci], bnj[ci], m);
            }
        unsigned long long* scr = (unsigned long long*)As;  // 1024 u64 = 8 KB
        __syncthreads();
        const int w = t >> 6;
        if ((t & 48) == 0) {
#pragma unroll
            for (int ci = 0; ci < 8; ++ci) {
                scr[w * 128 + lcol[ci]]       = pack_pos(bpv[ci], bpj[ci]);
                scr[512 + w * 128 + lcol[ci]] = pack_neg(bnv[ci], bnj[ci]);
            }
        }
        __syncthreads();
        if (t < 128) {
            unsigned long long mp = 0ULL, mn = ~0ULL;
#pragma unroll
            for (int ww = 0; ww < 4; ++ww) {
                const unsigned long long p = scr[ww * 128 + t];
                const unsigned long long q = scr[512 + ww * 128 + t];
                if (p > mp) mp = p;
                if (q < mn) mn = q;
            }
            atomicMax(&pos_pack[J0 + t], mp);
            atomicMin(&neg_pack[J0 + t], mn);
        }
    }
}

// ---------------------------------------------------------------------------
// Kernel 3: finalize -> int32 outputs [anchor | pos | neg | keep]
// ---------------------------------------------------------------------------
__global__ void finalize_kernel(const unsigned long long* __restrict__ pos_pack,
                                const unsigned long long* __restrict__ neg_pack,
                                const int* __restrict__ labels,
                                const int* __restrict__ hist,
                                int* __restrict__ out) {
    const int r = blockIdx.x * 256 + threadIdx.x;
    out[r]         = r;
    out[N + r]     = 8191 - (int)(pos_pack[r] & 0xFFFFFFFFULL);
    out[2 * N + r] = (int)(neg_pack[r] & 0xFFFFFFFFULL);
    const int cnt = hist[labels[r]];
    out[3 * N + r] = (cnt >= 2 && cnt < N) ? 1 : 0;
}

extern "C" void kernel_launch(void* const* d_in, const int* in_sizes, int n_in,
                              void* d_out, int out_size, void* d_ws, size_t ws_size,
                              hipStream_t stream) {
    const float* x      = (const float*)d_in[0];
    const int*   labels = (const int*)d_in[1];
    int* out = (int*)d_out;

    float* ws  = (float*)d_ws;
    float* xnT = ws;                                        // N*D floats (4 MB)
    float* sq  = xnT + (size_t)N * D;                       // N floats
    unsigned long long* pos_pack =
        (unsigned long long*)(sq + N);                      // N u64
    int* hist = (int*)(pos_pack + N);                       // NC ints
    unsigned long long* neg_pack =
        (unsigned long long*)(hist + NC);                   // N u64

    hipMemsetAsync(hist, 0, NC * 4, stream);
    normalize_kernel<<<N / 64, 256, 0, stream>>>(x, labels, xnT, sq, hist,
                                                 pos_pack, neg_pack);
    miner_kernel<<<NBLK, 256, 0, stream>>>(xnT, sq, labels, pos_pack, neg_pack);
    finalize_kernel<<<N / 256, 256, 0, stream>>>(pos_pack, neg_pack, labels, hist, out);
}

// Round 8
// 181.464 us; speedup vs baseline: 1.3050x; 1.3050x over previous
//
#include <hip/hip_runtime.h>
#include <math.h>

#define N 8192
#define D 128
#define NC 256
#define NT 64                    // 128-wide tiles per dim
#define NBLK (NT * (NT + 1) / 2) // 2080

typedef __attribute__((ext_vector_type(8))) short bf8;   // 8 bf16 = 4 VGPRs
typedef __attribute__((ext_vector_type(4))) float f4;    // MFMA acc

__device__ __forceinline__ unsigned short bf16_rtne(float f) {
    unsigned u = __float_as_uint(f);
    u += 0x7FFF + ((u >> 16) & 1);
    return (unsigned short)(u >> 16);
}
__device__ __forceinline__ float bf16_tof(unsigned short h) {
    return __uint_as_float((unsigned)h << 16);
}

// ---------------------------------------------------------------------------
// Kernel 1: normalize + 3-limb bf16 split (row-major), sq, histogram,
// best-pack init. x -> n = x/||x||; n = h1+h2+h3 + O(2^-24).
// ---------------------------------------------------------------------------
__global__ __launch_bounds__(256) void prep_kernel(
    const float* __restrict__ x, const int* __restrict__ labels,
    short* __restrict__ H,       // 3 limb matrices, H + l*N*D
    float* __restrict__ sq, int* __restrict__ hist,
    unsigned long long* __restrict__ pos_pack,
    unsigned long long* __restrict__ neg_pack) {
    __shared__ float Xs[64 * 129];
    const int t = threadIdx.x;
    const int r0 = blockIdx.x * 64;

    {   // init best-packs: 128 blocks x 256 threads cover 8192
        const int g = blockIdx.x * 256 + t;
        if (g < N) { pos_pack[g] = 0ULL; neg_pack[g] = ~0ULL; }
    }

    // load 64x128 block
#pragma unroll
    for (int p = 0; p < 8; ++p) {
        const int lin = p * 256 + t;
        const int row = lin >> 5;
        const int c0 = (lin & 31) << 2;
        const float4 v = *(const float4*)(x + (size_t)(r0 + row) * D + c0);
        float* dst = &Xs[row * 129 + c0];
        dst[0] = v.x; dst[1] = v.y; dst[2] = v.z; dst[3] = v.w;
    }
    __syncthreads();

    // 4 threads/row: norm, sq of normalized, limb emission
    const int r = t >> 2, q2 = t & 3;
    const float* src = &Xs[r * 129 + q2 * 32];
    float s = 0.f;
#pragma unroll
    for (int i = 0; i < 32; ++i) s = fmaf(src[i], src[i], s);
    s += __shfl_xor(s, 1, 64);
    s += __shfl_xor(s, 2, 64);
    const float nrm = sqrtf(s);
    float t2 = 0.f;
#pragma unroll
    for (int i = 0; i < 32; ++i) {
        const float n = src[i] / nrm;
        t2 = fmaf(n, n, t2);
    }
    t2 += __shfl_xor(t2, 1, 64);
    t2 += __shfl_xor(t2, 2, 64);
    if (q2 == 0) sq[r0 + r] = t2;

    // limb split, 8B-coalesced stores (wave = 16 rows x 256 B contiguous)
    const size_t gbase = (size_t)(r0 + r) * D + q2 * 32;
#pragma unroll
    for (int g = 0; g < 8; ++g) {
        short4 o1, o2, o3;
        short* p1 = (short*)&o1; short* p2 = (short*)&o2; short* p3 = (short*)&o3;
#pragma unroll
        for (int i = 0; i < 4; ++i) {
            const float n = src[g * 4 + i] / nrm;
            const unsigned short h1 = bf16_rtne(n);
            const float r1 = n - bf16_tof(h1);
            const unsigned short h2 = bf16_rtne(r1);
            const float r2 = r1 - bf16_tof(h2);
            const unsigned short h3 = bf16_rtne(r2);
            p1[i] = (short)h1; p2[i] = (short)h2; p3[i] = (short)h3;
        }
        *(short4*)(H + gbase + g * 4)                     = o1;
        *(short4*)(H + (size_t)N * D + gbase + g * 4)     = o2;
        *(short4*)(H + (size_t)2 * N * D + gbase + g * 4) = o3;
    }

    if (t < 64) atomicAdd(&hist[labels[r0 + t]], 1);
}

// ---------------------------------------------------------------------------
// Kernel 2: symmetric 128x128-tile Gram via 3-limb bf16 MFMA (6 limb-pair
// products), fused arg-reductions. mfma_f32_16x16x32_bf16 layouts (HW-
// verified): A[m=lane&15][k=quad*8+j]; B symmetric; C/D col=lane&15,
// row=quad*4+reg. Wave w owns rows w*32..+32 of the tile, all 128 cols.
// ---------------------------------------------------------------------------
__device__ __forceinline__ unsigned int fbits(float f) {
    union { float f; unsigned int u; } x; x.f = f; return x.u;
}
__device__ __forceinline__ unsigned long long pack_pos(float v, int j) {
    return ((unsigned long long)fbits(v) << 32) | (unsigned int)(8191 - j);
}
__device__ __forceinline__ unsigned long long pack_neg(float v, int j) {
    return ((unsigned long long)fbits(v) << 32) | (unsigned int)j;
}
__device__ __forceinline__ void red_max(float& v, int& j, int mask) {
    const float ov = __shfl_xor(v, mask, 64);
    const int   oj = __shfl_xor(j, mask, 64);
    if (ov > v || (ov == v && oj < j)) { v = ov; j = oj; }
}
__device__ __forceinline__ void red_min(float& v, int& j, int mask) {
    const float ov = __shfl_xor(v, mask, 64);
    const int   oj = __shfl_xor(j, mask, 64);
    if (ov < v || (ov == v && oj < j)) { v = ov; j = oj; }
}

__global__ __launch_bounds__(256) void miner_kernel(
    const short* __restrict__ H, const float* __restrict__ sq,
    const int* __restrict__ labels,
    unsigned long long* __restrict__ pos_pack,
    unsigned long long* __restrict__ neg_pack) {
    __shared__ __align__(16) short sA[3 * 128 * 32];  // 24 KB; reused as u64 scratch
    __shared__ __align__(16) short sB[3 * 128 * 32];  // 24 KB
    __shared__ float sqI[128], sqJ[128];
    __shared__ int   lbI[128], lbJ[128];

    const int t = threadIdx.x;
    const int w = t >> 6;       // wave id: rows w*32..w*32+31
    const int l = t & 63;
    const int quad = l >> 4;
    const int l16 = l & 15;

    // decode upper-triangular (bi, bj), bi <= bj, NT=64
    const int b = blockIdx.x;
    int bi = (int)((129.0f - sqrtf(16641.0f - 8.0f * (float)b)) * 0.5f);
    while (bi > 0 && (bi * NT - bi * (bi - 1) / 2) > b) --bi;
    while (((bi + 1) * NT - (bi + 1) * bi / 2) <= b) ++bi;
    const int bj = bi + (b - (bi * NT - bi * (bi - 1) / 2));
    const int I0 = bi * 128, J0 = bj * 128;
    const bool diag = (bi == bj);

    if (t < 128) { sqI[t] = sq[I0 + t]; lbI[t] = labels[I0 + t]; }
    else         { sqJ[t - 128] = sq[J0 + t - 128]; lbJ[t - 128] = labels[J0 + t - 128]; }

    f4 acc[2][8];
#pragma unroll
    for (int rt = 0; rt < 2; ++rt)
#pragma unroll
        for (int ct = 0; ct < 8; ++ct) acc[rt][ct] = (f4){0.f, 0.f, 0.f, 0.f};

    for (int q = 0; q < 4; ++q) {
        const int kc = q * 32;
        __syncthreads();
        // stage 48 KB: [limb][sample][32k] bf16, both panels; 16B/thread x 12
#pragma unroll
        for (int p = 0; p < 12; ++p) {
            const int c = p * 256 + t;          // 0..3071
            const int limb = c >> 10;
            const int rem  = c & 1023;
            const int side = rem >> 9;
            const int cc   = rem & 511;
            const int sample = cc >> 2;
            const int sub    = cc & 3;
            const short* gsrc = H + (size_t)limb * N * D +
                                (size_t)((side ? J0 : I0) + sample) * D + kc + sub * 8;
            short* ldst = (side ? sB : sA) + (limb * 128 + sample) * 32 + sub * 8;
            *(bf8*)ldst = *(const bf8*)gsrc;
        }
        __syncthreads();

        // all 6 A-fragments (3 limbs x 2 row-tiles); wave-contiguous 1KB reads
        bf8 aF[3][2];
#pragma unroll
        for (int limb = 0; limb < 3; ++limb)
#pragma unroll
            for (int rt = 0; rt < 2; ++rt)
                aF[limb][rt] = *(const bf8*)
                    &sA[(limb * 128 + w * 32 + rt * 16 + l16) * 32 + quad * 8];

#pragma unroll
        for (int lb = 0; lb < 3; ++lb) {
            bf8 bF[8];
#pragma unroll
            for (int ct = 0; ct < 8; ++ct)
                bF[ct] = *(const bf8*)
                    &sB[(lb * 128 + ct * 16 + l16) * 32 + quad * 8];
#pragma unroll
            for (int la = 0; la + lb < 3; ++la)      // limb pairs la+lb <= 2
#pragma unroll
                for (int rt = 0; rt < 2; ++rt)
#pragma unroll
                    for (int ct = 0; ct < 8; ++ct)
                        acc[rt][ct] = __builtin_amdgcn_mfma_f32_16x16x32_bf16(
                            aF[la][rt], bF[ct], acc[rt][ct], 0, 0, 0);
        }
    }

    // ---- epilogue ----
    float sjv[8]; int ljv[8];
#pragma unroll
    for (int ct = 0; ct < 8; ++ct) {
        sjv[ct] = sqJ[ct * 16 + l16];
        ljv[ct] = lbJ[ct * 16 + l16];
    }

    // I-side: rows w*32+rt*16+quad*4+r; candidates over ct then l16-lanes
#pragma unroll
    for (int rt = 0; rt < 2; ++rt)
#pragma unroll
        for (int r = 0; r < 4; ++r) {
            const int lr = w * 32 + rt * 16 + quad * 4 + r;
            const float si = sqI[lr];
            const int   liv = lbI[lr];
            const int   grow = I0 + lr;
            float bpv = -1.0f, bnv = INFINITY; int bpj = 0, bnj = 0;
#pragma unroll
            for (int ct = 0; ct < 8; ++ct) {
                const float d2 = fmaxf(si + sjv[ct] - 2.0f * acc[rt][ct][r], 0.0f);
                const int col = J0 + ct * 16 + l16;
                const bool same = (liv == ljv[ct]);
                const float vp = (same && grow != col) ? d2 : 0.0f;
                if (vp > bpv) { bpv = vp; bpj = col; }
                const float vn = same ? INFINITY : d2;
                if (vn < bnv) { bnv = vn; bnj = col; }
            }
            red_max(bpv, bpj, 1); red_max(bpv, bpj, 2);
            red_max(bpv, bpj, 4); red_max(bpv, bpj, 8);
            red_min(bnv, bnj, 1); red_min(bnv, bnj, 2);
            red_min(bnv, bnj, 4); red_min(bnv, bnj, 8);
            if (l16 == 0) {
                atomicMax(&pos_pack[grow], pack_pos(bpv, bpj));
                atomicMin(&neg_pack[grow], pack_neg(bnv, bnj));
            }
        }

    // J-side (skip on diagonal): per-col best over this wave's 32 rows,
    // reduce over quad (masks 16,32), cross-wave merge via LDS, commit.
    if (!diag) {
        float bpv[8], bnv[8]; int bpj[8], bnj[8];
#pragma unroll
        for (int ct = 0; ct < 8; ++ct) {
            bpv[ct] = -1.0f; bpj[ct] = 0; bnv[ct] = INFINITY; bnj[ct] = 0;
#pragma unroll
            for (int rt = 0; rt < 2; ++rt)
#pragma unroll
                for (int r = 0; r < 4; ++r) {
                    const int lr = w * 32 + rt * 16 + quad * 4 + r;
                    const float d2 =
                        fmaxf(sqI[lr] + sjv[ct] - 2.0f * acc[rt][ct][r], 0.0f);
                    const int row = I0 + lr;
                    const bool same = (lbI[lr] == ljv[ct]);  // no self off-diag
                    const float vp = same ? d2 : 0.0f;
                    if (vp > bpv[ct]) { bpv[ct] = vp; bpj[ct] = row; }
                    const float vn = same ? INFINITY : d2;
                    if (vn < bnv[ct]) { bnv[ct] = vn; bnj[ct] = row; }
                }
#pragma unroll
            for (int m = 16; m < 64; m <<= 1) {
                red_max(bpv[ct], bpj[ct], m);
                red_min(bnv[ct], bnj[ct], m);
            }
        }
        unsigned long long* scr = (unsigned long long*)sA;  // 8 KB scratch
        __syncthreads();
        if (quad == 0) {
#pragma unroll
            for (int ct = 0; ct < 8; ++ct) {
                scr[w * 128 + ct * 16 + l16]       = pack_pos(bpv[ct], bpj[ct]);
                scr[512 + w * 128 + ct * 16 + l16] = pack_neg(bnv[ct], bnj[ct]);
            }
        }
        __syncthreads();
        if (t < 128) {
            unsigned long long mp = 0ULL, mn = ~0ULL;
#pragma unroll
            for (int ww = 0; ww < 4; ++ww) {
                const unsigned long long p = scr[ww * 128 + t];
                const unsigned long long qq = scr[512 + ww * 128 + t];
                if (p > mp) mp = p;
                if (qq < mn) mn = qq;
            }
            atomicMax(&pos_pack[J0 + t], mp);
            atomicMin(&neg_pack[J0 + t], mn);
        }
    }
}

// ---------------------------------------------------------------------------
// Kernel 3: finalize -> int32 outputs [anchor | pos | neg | keep]
// ---------------------------------------------------------------------------
__global__ void finalize_kernel(const unsigned long long* __restrict__ pos_pack,
                                const unsigned long long* __restrict__ neg_pack,
                                const int* __restrict__ labels,
                                const int* __restrict__ hist,
                                int* __restrict__ out) {
    const int r = blockIdx.x * 256 + threadIdx.x;
    out[r]         = r;
    out[N + r]     = 8191 - (int)(pos_pack[r] & 0xFFFFFFFFULL);
    out[2 * N + r] = (int)(neg_pack[r] & 0xFFFFFFFFULL);
    const int cnt = hist[labels[r]];
    out[3 * N + r] = (cnt >= 2 && cnt < N) ? 1 : 0;
}

extern "C" void kernel_launch(void* const* d_in, const int* in_sizes, int n_in,
                              void* d_out, int out_size, void* d_ws, size_t ws_size,
                              hipStream_t stream) {
    const float* x      = (const float*)d_in[0];
    const int*   labels = (const int*)d_in[1];
    int* out = (int*)d_out;

    short* H = (short*)d_ws;                                // 3*N*D bf16 = 6 MB
    float* sq = (float*)(H + (size_t)3 * N * D);            // N floats
    unsigned long long* pos_pack =
        (unsigned long long*)(sq + N);                      // N u64
    int* hist = (int*)(pos_pack + N);                       // NC ints
    unsigned long long* neg_pack =
        (unsigned long long*)(hist + NC);                   // N u64

    hipMemsetAsync(hist, 0, NC * 4, stream);
    prep_kernel<<<N / 64, 256, 0, stream>>>(x, labels, H, sq, hist,
                                            pos_pack, neg_pack);
    miner_kernel<<<NBLK, 256, 0, stream>>>(H, sq, labels, pos_pack, neg_pack);
    finalize_kernel<<<N / 256, 256, 0, stream>>>(pos_pack, neg_pack, labels, hist, out);
}